// Round 5
// baseline (584.042 us; speedup 1.0000x reference)
//
#include <hip/hip_runtime.h>

// Problem constants
#define BATCH 64
#define SEQ   577
#define CDIM  768
#define NH    12
#define HD    64
#define MROWS (BATCH * SEQ)      // 36928
#define KDIM  768
#define QKV_N (3 * CDIM)         // 2304
#define NPAD  640                // vt row length (multiple of 64)
#define TQ    128                // flash q-tile rows per block
#define PS    40                 // sP row stride (u16)
#define OS    72                 // O-repack row stride (u16)
#define DEAD_ROW0 18560          // first fully-dead (b>=32) 128-row tile start
#define ROWT  289                // ceil(MROWS/128)
#define RPX   37                 // row-tiles per XCD (ceil(289/8))

typedef short bf16x8 __attribute__((ext_vector_type(8)));
typedef float f32x4  __attribute__((ext_vector_type(4)));

__device__ __forceinline__ unsigned short f2bf(float f) {
  unsigned int u = __float_as_uint(f);
  u += 0x7fffu + ((u >> 16) & 1u);   // round-to-nearest-even
  return (unsigned short)(u >> 16);
}

__device__ __forceinline__ void async_ld16(const unsigned short* g, unsigned short* l) {
  __builtin_amdgcn_global_load_lds((const __attribute__((address_space(1))) void*)g,
                                   (__attribute__((address_space(3))) void*)l, 16, 0, 0);
}

// ---------------- fp32 -> bf16 conversion ----------------
__global__ __launch_bounds__(256) void cvt_bf16(const float* __restrict__ in,
                                                unsigned short* __restrict__ out, int n4) {
  int i = blockIdx.x * 256 + threadIdx.x;
  if (i < n4) {
    float4 f = ((const float4*)in)[i];
    ushort4 o = make_ushort4(f2bf(f.x), f2bf(f.y), f2bf(f.z), f2bf(f.w));
    ((ushort4*)out)[i] = o;
  }
}

// ---------------- QKV GEMM: [MROWS,768] x [2304,768]^T -> q/k/v [B,H,N,D] bf16 ----
// 1D grid, XCD-decomposed: xcd=id&7 owns RPX row-tiles, col-tile varies fastest so the
// 3.5 MB weight matrix stays L2-resident per XCD and each A-tile is reused 18x in L2.
__global__ __launch_bounds__(256) void gemm_qkv(
    const unsigned short* __restrict__ A,
    const unsigned short* __restrict__ Bm,
    unsigned short* __restrict__ qb,
    unsigned short* __restrict__ kb,
    unsigned short* __restrict__ vb) {
  const int id = blockIdx.x;
  const int xcd = id & 7;
  const int j = id >> 3;
  const int colt = j % 18;
  const int rowt = xcd * RPX + j / 18;
  if (rowt >= ROWT) return;
  const int row0 = rowt * 128;
  const int col0 = colt * 128;
  // dead-head skip: rows all b>=32 and channels h>=6 -> never read downstream
  if (row0 >= DEAD_ROW0 && (col0 % CDIM) >= (CDIM / 2)) return;

  __shared__ unsigned short sA[128 * 32];
  __shared__ unsigned short sB[128 * 32];
  const int tid = threadIdx.x;
  const int w = tid >> 6, lane = tid & 63;
  const int quad = lane >> 4, l16 = lane & 15;
  const int wr = w >> 1, wc = w & 1;

  f32x4 acc[4][4] = {};

  for (int kt = 0; kt < KDIM; kt += 32) {
    __syncthreads();
    #pragma unroll
    for (int c = 0; c < 2; c++) {
      int i = tid + c * 256;            // chunk id 0..511; 128 rows x 4 chunks
      int r = i >> 2, k8 = (i & 3) * 8;
      int ibase = (tid & ~63) + c * 256;
      int gr = row0 + r; if (gr >= MROWS) gr = MROWS - 1;
      async_ld16(A + gr * KDIM + kt + k8, sA + ibase * 8);
      int gc = col0 + r;
      async_ld16(Bm + gc * KDIM + kt + k8, sB + ibase * 8);
    }
    __syncthreads();

    bf16x8 af[4], bfv[4];
    #pragma unroll
    for (int i = 0; i < 4; i++)
      af[i] = *(const bf16x8*)&sA[(wr * 64 + i * 16 + l16) * 32 + quad * 8];
    #pragma unroll
    for (int j2 = 0; j2 < 4; j2++)
      bfv[j2] = *(const bf16x8*)&sB[(wc * 64 + j2 * 16 + l16) * 32 + quad * 8];
    #pragma unroll
    for (int i = 0; i < 4; i++)
      #pragma unroll
      for (int j2 = 0; j2 < 4; j2++)
        acc[i][j2] = __builtin_amdgcn_mfma_f32_16x16x32_bf16(af[i], bfv[j2], acc[i][j2], 0, 0, 0);
  }

  #pragma unroll
  for (int i = 0; i < 4; i++) {
    int mbase = row0 + wr * 64 + i * 16 + quad * 4;
    #pragma unroll
    for (int j2 = 0; j2 < 4; j2++) {
      int col = col0 + wc * 64 + j2 * 16 + l16;
      int three = col / CDIM;
      int rem = col - three * CDIM;
      int h = rem >> 6, d = rem & 63;
      unsigned short* dst = (three == 0) ? qb : (three == 1) ? kb : vb;
      float sc = (three == 0) ? 0.180336878f : 1.0f;  // 0.125 * log2(e)
      #pragma unroll
      for (int r = 0; r < 4; r++) {
        int m = mbase + r;
        if (m < MROWS) {
          int b = m / SEQ;
          int n = m - b * SEQ;
          dst[(((b * NH + h) * SEQ + n) << 6) + d] = f2bf(acc[i][j2][r] * sc);
        }
      }
    }
  }
}

// ---------------- V transpose: v[bh][n][64] -> vt[bh][64][NPAD], zero pads ----------------
__global__ __launch_bounds__(512) void transpose_v(
    const unsigned short* __restrict__ v,
    unsigned short* __restrict__ vt) {
  const int bh = blockIdx.y;
  const int b = bh / NH, h = bh - b * NH;
  if (b >= 32 && h >= 6) return;
  const int t = blockIdx.x;               // 0..9
  const int tid = threadIdx.x;
  const int w = tid >> 6, lane = tid & 63; // w = d8 index 0..7
  int n = t * 64 + lane;
  bf16x8 vv = {};
  if (n < SEQ)
    vv = *(const bf16x8*)&v[(size_t)bh * (SEQ * HD) + n * HD + w * 8];
  unsigned short* dst = vt + (size_t)bh * (HD * NPAD) + (w * 8) * NPAD + t * 64 + lane;
  #pragma unroll
  for (int j = 0; j < 8; j++)
    dst[j * NPAD] = ((const unsigned short*)&vv)[j];
}

// ---------------- Flash attention (no-max softmax, MFMA row-sum) ----------------
__global__ __launch_bounds__(256, 4) void flash_attn(
    const unsigned short* __restrict__ q,   // pre-scaled by 0.125*log2e
    const unsigned short* __restrict__ k,
    const unsigned short* __restrict__ vt,  // [BH][64][NPAD], zero-padded
    unsigned short* __restrict__ attn) {    // [B, N, C] bf16
  const int id = blockIdx.x;
  const int bh8 = id / 40;
  const int rem = id - bh8 * 40;
  const int qt = rem >> 3;
  const int bh = bh8 * 8 + (rem & 7);
  const int b = bh / NH, h = bh - b * NH;
  const int tid = threadIdx.x;
  const int w = tid >> 6, lane = tid & 63;
  const int quad = lane >> 4, l16 = lane & 15;

  if (b >= 32 && h >= 6) {
    for (int it = tid; it < TQ * 8; it += 256) {
      int r = it >> 3, c8 = (it & 7) * 8;
      int n = qt * TQ + r;
      if (n < SEQ)
        *(int4*)&attn[(b * SEQ + n) * CDIM + h * 64 + c8] = make_int4(0, 0, 0, 0);
    }
    return;
  }

  __shared__ unsigned short sK[2 * 64 * 32];    // [d-half][kv][32]
  __shared__ unsigned short sVt[2 * 64 * 32];   // [kv-half][d][32]
  __shared__ unsigned short sP[4][64 * PS];     // [wave][(g*2+hf)*16+row][PS]

  const unsigned short* qbase = q + (size_t)bh * (SEQ * HD);
  const unsigned short* kbase = k + (size_t)bh * (SEQ * HD);
  const unsigned short* vtbase = vt + (size_t)bh * (HD * NPAD);

  bf16x8 aq[2][2];
  #pragma unroll
  for (int g = 0; g < 2; g++) {
    int qr = qt * TQ + w * 32 + g * 16 + l16;
    if (qr > SEQ - 1) qr = SEQ - 1;
    aq[g][0] = *(const bf16x8*)&qbase[qr * HD + quad * 8];
    aq[g][1] = *(const bf16x8*)&qbase[qr * HD + 32 + quad * 8];
  }

  f32x4 oacc[2][4] = {};
  f32x4 lacc[2] = {};   // row-sum accumulator via ones-fragment MFMA

  const short ONE = (short)0x3F80;  // bf16 1.0

  for (int t = 0; t < 10; t++) {
    __syncthreads();
    #pragma unroll
    for (int c = 0; c < 2; c++) {
      int rI = tid >> 2, c4 = tid & 3;
      int base = c * 2048 + (tid & ~63) * 8;
      int kr = t * 64 + rI; if (kr > SEQ - 1) kr = SEQ - 1;
      async_ld16(kbase + kr * HD + c * 32 + c4 * 8, sK + base);
      async_ld16(vtbase + rI * NPAD + t * 64 + c * 32 + c4 * 8, sVt + base);
    }
    __syncthreads();

    bf16x8 bk[4][2];
    #pragma unroll
    for (int nt = 0; nt < 4; nt++) {
      bk[nt][0] = *(const bf16x8*)&sK[0 * 2048 + (nt * 16 + l16) * 32 + quad * 8];
      bk[nt][1] = *(const bf16x8*)&sK[1 * 2048 + (nt * 16 + l16) * 32 + quad * 8];
    }

    // ones B-fragment: B[n][k]=1 for valid kv, else 0 (tile 9: only kv==576 valid)
    bf16x8 ones0, ones1;
    if (t < 9) {
      #pragma unroll
      for (int j = 0; j < 8; j++) { ones0[j] = ONE; ones1[j] = ONE; }
    } else {
      bf16x8 z = {};
      ones0 = z; ones1 = z;
      ones0[0] = (quad == 0) ? ONE : (short)0;
    }

    #pragma unroll
    for (int g = 0; g < 2; g++) {
      f32x4 s[4];
      #pragma unroll
      for (int nt = 0; nt < 4; nt++) {
        f32x4 z = {};
        z = __builtin_amdgcn_mfma_f32_16x16x32_bf16(aq[g][0], bk[nt][0], z, 0, 0, 0);
        z = __builtin_amdgcn_mfma_f32_16x16x32_bf16(aq[g][1], bk[nt][1], z, 0, 0, 0);
        s[nt] = z;
      }
      #pragma unroll
      for (int nt = 0; nt < 4; nt++)
        #pragma unroll
        for (int r = 0; r < 4; r++)
          sP[w][((g * 2 + (nt >> 1)) * 16 + quad * 4 + r) * PS + (nt & 1) * 16 + l16] =
              f2bf(__builtin_exp2f(s[nt][r]));
    }

    #pragma unroll
    for (int g = 0; g < 2; g++) {
      bf16x8 pa0 = *(const bf16x8*)&sP[w][((g * 2 + 0) * 16 + l16) * PS + quad * 8];
      bf16x8 pa1 = *(const bf16x8*)&sP[w][((g * 2 + 1) * 16 + l16) * PS + quad * 8];
      #pragma unroll
      for (int dt = 0; dt < 4; dt++) {
        bf16x8 bv0 = *(const bf16x8*)&sVt[0 * 2048 + (dt * 16 + l16) * 32 + quad * 8];
        bf16x8 bv1 = *(const bf16x8*)&sVt[1 * 2048 + (dt * 16 + l16) * 32 + quad * 8];
        oacc[g][dt] = __builtin_amdgcn_mfma_f32_16x16x32_bf16(pa0, bv0, oacc[g][dt], 0, 0, 0);
        oacc[g][dt] = __builtin_amdgcn_mfma_f32_16x16x32_bf16(pa1, bv1, oacc[g][dt], 0, 0, 0);
      }
      lacc[g] = __builtin_amdgcn_mfma_f32_16x16x32_bf16(pa0, ones0, lacc[g], 0, 0, 0);
      lacc[g] = __builtin_amdgcn_mfma_f32_16x16x32_bf16(pa1, ones1, lacc[g], 0, 0, 0);
    }
  }

  // normalize + repack O through LDS -> coalesced b128 stores
  unsigned short* so = &sP[w][0];   // viewed as [32][OS]
  #pragma unroll
  for (int g = 0; g < 2; g++)
    #pragma unroll
    for (int r = 0; r < 4; r++) {
      float inv = 1.0f / lacc[g][r];
      #pragma unroll
      for (int dt = 0; dt < 4; dt++)
        so[(g * 16 + quad * 4 + r) * OS + dt * 16 + l16] = f2bf(oacc[g][dt][r] * inv);
    }
  #pragma unroll
  for (int it = 0; it < 4; it++) {
    int chunk = it * 64 + lane;
    int row = chunk >> 3, c8 = chunk & 7;
    int n = qt * TQ + w * 32 + row;
    if (n < SEQ)
      *(int4*)&attn[(b * SEQ + n) * CDIM + h * 64 + c8 * 8] =
          *(const int4*)&so[row * OS + c8 * 8];
  }
}

// ---------------- Proj GEMM: attn[MROWS,768] x [768,768]^T + bias -> fp32 out ----
// Same XCD decomposition: weights (1.2 MB) L2-resident, A-tile reused across 6 col-blocks.
__global__ __launch_bounds__(256) void gemm_proj(
    const unsigned short* __restrict__ A,
    const unsigned short* __restrict__ Bm,
    const float* __restrict__ bias,
    float* __restrict__ out) {
  const int id = blockIdx.x;
  const int xcd = id & 7;
  const int j = id >> 3;
  const int colt = j % 6;
  const int rowt = xcd * RPX + j / 6;
  if (rowt >= ROWT) return;
  const int row0 = rowt * 128;
  const int col0 = colt * 128;
  const int tid = threadIdx.x;

  if (row0 >= DEAD_ROW0 && col0 >= (CDIM / 2)) {
    float4 z4 = make_float4(0.f, 0.f, 0.f, 0.f);
    #pragma unroll
    for (int it = 0; it < 16; it++) {
      int idx = it * 256 + tid;
      int r = idx >> 5, c4 = idx & 31;
      int m = row0 + r;
      if (m < MROWS)
        *(float4*)&out[(size_t)m * CDIM + col0 + c4 * 4] = z4;
    }
    return;
  }

  __shared__ unsigned short sA[128 * 32];
  __shared__ unsigned short sB[128 * 32];
  const int w = tid >> 6, lane = tid & 63;
  const int quad = lane >> 4, l16 = lane & 15;
  const int wr = w >> 1, wc = w & 1;

  f32x4 acc[4][4] = {};

  for (int kt = 0; kt < KDIM; kt += 32) {
    __syncthreads();
    #pragma unroll
    for (int c = 0; c < 2; c++) {
      int i = tid + c * 256;
      int r = i >> 2, k8 = (i & 3) * 8;
      int ibase = (tid & ~63) + c * 256;
      int gr = row0 + r; if (gr >= MROWS) gr = MROWS - 1;
      async_ld16(A + gr * KDIM + kt + k8, sA + ibase * 8);
      int gc = col0 + r;
      async_ld16(Bm + gc * KDIM + kt + k8, sB + ibase * 8);
    }
    __syncthreads();

    bf16x8 af[4], bfv[4];
    #pragma unroll
    for (int i = 0; i < 4; i++)
      af[i] = *(const bf16x8*)&sA[(wr * 64 + i * 16 + l16) * 32 + quad * 8];
    #pragma unroll
    for (int j2 = 0; j2 < 4; j2++)
      bfv[j2] = *(const bf16x8*)&sB[(wc * 64 + j2 * 16 + l16) * 32 + quad * 8];
    #pragma unroll
    for (int i = 0; i < 4; i++)
      #pragma unroll
      for (int j2 = 0; j2 < 4; j2++)
        acc[i][j2] = __builtin_amdgcn_mfma_f32_16x16x32_bf16(af[i], bfv[j2], acc[i][j2], 0, 0, 0);
  }

  #pragma unroll
  for (int i = 0; i < 4; i++) {
    int mbase = row0 + wr * 64 + i * 16 + quad * 4;
    #pragma unroll
    for (int j2 = 0; j2 < 4; j2++) {
      int col = col0 + wc * 64 + j2 * 16 + l16;
      float bv = bias[col];
      #pragma unroll
      for (int r = 0; r < 4; r++) {
        int m = mbase + r;
        if (m < MROWS) {
          int b = m / SEQ;
          float val = acc[i][j2][r] + bv;
          if (b >= 32 && col >= (CDIM / 2)) val = 0.f;
          out[(size_t)m * CDIM + col] = val;
        }
      }
    }
  }
}

extern "C" void kernel_launch(void* const* d_in, const int* in_sizes, int n_in,
                              void* d_out, int out_size, void* d_ws, size_t ws_size,
                              hipStream_t stream) {
  const float* x      = (const float*)d_in[0];
  const float* qkv_w  = (const float*)d_in[1];
  const float* proj_w = (const float*)d_in[2];
  const float* proj_b = (const float*)d_in[3];
  float* out = (float*)d_out;

  size_t off = 0;
  auto alloc = [&](size_t bytes) {
    void* p = (char*)d_ws + off;
    off += (bytes + 255) & ~(size_t)255;
    return p;
  };
  const size_t XE = (size_t)MROWS * KDIM;
  unsigned short* xb   = (unsigned short*)alloc(XE * 2);
  unsigned short* wqb  = (unsigned short*)alloc((size_t)QKV_N * KDIM * 2);
  unsigned short* wpb  = (unsigned short*)alloc((size_t)CDIM * KDIM * 2);
  unsigned short* qb   = (unsigned short*)alloc(XE * 2);
  unsigned short* kb   = (unsigned short*)alloc(XE * 2);
  unsigned short* vb   = (unsigned short*)alloc(XE * 2);
  unsigned short* vtb  = (unsigned short*)alloc((size_t)BATCH * NH * HD * NPAD * 2);
  unsigned short* attnb = xb;   // xb dead after gemm_qkv
  (void)ws_size;

  cvt_bf16<<<(int)(XE / 4 / 256), 256, 0, stream>>>(x, xb, (int)(XE / 4));
  cvt_bf16<<<(QKV_N * KDIM / 4) / 256, 256, 0, stream>>>(qkv_w, wqb, QKV_N * KDIM / 4);
  cvt_bf16<<<(CDIM * KDIM / 4) / 256, 256, 0, stream>>>(proj_w, wpb, CDIM * KDIM / 4);

  gemm_qkv<<<8 * RPX * 18, 256, 0, stream>>>(xb, wqb, qb, kb, vb);

  transpose_v<<<dim3(10, BATCH * NH), 512, 0, stream>>>(vb, vtb);

  flash_attn<<<(BATCH * NH / 8) * 40, 256, 0, stream>>>(qb, kb, vtb, attnb);

  gemm_proj<<<8 * RPX * 6, 256, 0, stream>>>(attnb, wpb, proj_b, out);
}